// Round 7
// baseline (661.806 us; speedup 1.0000x reference)
//
#include <hip/hip_runtime.h>
#include <cstdint>
#include <cmath>

#define HID 768
#define INNER 1536
#define NST 16
#define SEQ 2048
#define BATCH 2
#define MTOK 4096      // BATCH*SEQ
#define CHUNK 32
#define NCHUNK 64      // SEQ/CHUNK
#define LOG2E 1.44269504088896f

typedef unsigned short u16;
typedef __bf16 bf16x8 __attribute__((ext_vector_type(8)));
typedef float f32x4 __attribute__((ext_vector_type(4)));
typedef u16 u16x8 __attribute__((ext_vector_type(8)));

__device__ __forceinline__ u16 f2b(float f) {
  union { float f; unsigned u; } a; a.f = f;
  unsigned r = a.u + 0x7FFFu + ((a.u >> 16) & 1u);
  return (u16)(r >> 16);
}
__device__ __forceinline__ float b2f(u16 h) {
  union { unsigned u; float f; } a; a.u = ((unsigned)h) << 16; return a.f;
}

// packed fragment layout: element (m,k) of an [M][K] bf16 matrix lives at
//   chunk = ((m>>4)*KS + (k>>5))*64 + ((k>>3)&3)*16 + (m&15),  elem = chunk*8 + (k&7)
// where KS = K/32. Tile t, kstep ks = contiguous 1KB block.
__device__ __forceinline__ long pidx(long m, int k, int KS) {
  return (((m >> 4) * (long)KS + (k >> 5)) * 64 + ((k >> 3) & 3) * 16 + (m & 15)) * 8 + (k & 7);
}

// ---------------- LayerNorm + cast to bf16 (packed, KS=24) ----------------
__global__ __launch_bounds__(256)
void ln_kernel(const float* __restrict__ x, const float* __restrict__ w,
               const float* __restrict__ b, u16* __restrict__ xnp) {
  const long row = blockIdx.x;
  const float* xr = x + row * HID;
  const int t = threadIdx.x;
  float v0 = xr[t], v1 = xr[t + 256], v2 = xr[t + 512];
  float s1 = v0 + v1 + v2;
  float s2 = v0 * v0 + v1 * v1 + v2 * v2;
#pragma unroll
  for (int o = 32; o > 0; o >>= 1) { s1 += __shfl_down(s1, o); s2 += __shfl_down(s2, o); }
  __shared__ float r1[4], r2[4];
  if ((t & 63) == 0) { r1[t >> 6] = s1; r2[t >> 6] = s2; }
  __syncthreads();
  s1 = r1[0] + r1[1] + r1[2] + r1[3];
  s2 = r2[0] + r2[1] + r2[2] + r2[3];
  const float mu = s1 * (1.f / HID);
  float var = s2 * (1.f / HID) - mu * mu;
  const float rs = rsqrtf(var + 1e-5f);
  xnp[pidx(row, t,       24)] = f2b((v0 - mu) * rs * w[t]       + b[t]);
  xnp[pidx(row, t + 256, 24)] = f2b((v1 - mu) * rs * w[t + 256] + b[t + 256]);
  xnp[pidx(row, t + 512, 24)] = f2b((v2 - mu) * rs * w[t + 512] + b[t + 512]);
}

// ---------------- fp32 W[K][N] -> packed bf16 fragments (B-operand) ----------------
__global__ __launch_bounds__(256)
void pack_w(const float* __restrict__ W, u16* __restrict__ Bp, int K, int N) {
  __shared__ float tb[32][65];
  const int t = threadIdx.x;
  const int n0 = blockIdx.x * 64;
  const int ks = blockIdx.y;
  const int k0 = ks * 32;
  const int KS = K >> 5;
  {
    const int col = t & 63, row0 = t >> 6;
    const int nn = n0 + col;
#pragma unroll
    for (int rr = 0; rr < 8; ++rr) {
      const int kk = k0 + row0 + rr * 4;
      tb[row0 + rr * 4][col] = (nn < N) ? W[(long)kk * N + nn] : 0.f;
    }
  }
  __syncthreads();
  const int ntl = t >> 6, l4 = (t >> 4) & 3, l16 = t & 15;
  const int nl = ntl * 16 + l16;
  u16x8 outv;
#pragma unroll
  for (int wdx = 0; wdx < 8; ++wdx) outv[wdx] = f2b(tb[l4 * 8 + wdx][nl]);
  const long tile = (n0 >> 4) + ntl;
  *(u16x8*)&Bp[(tile * KS + ks) * 512 + (l4 * 16 + l16) * 8] = outv;
}

// ---------------- AITER-style pipelined GEMM: 128x128 tile, LDS dbuf ------------
// 3-stage pipeline: global->VGPR (tile k+2), VGPR->LDS (tile k+1), LDS->MFMA (k).
// One raw s_barrier per iter; only lgkmcnt drained at it. The compiler's
// register-precise vmcnt(N) before ds_write keeps the newer 4 loads in flight
// across the barrier (no vmcnt(0) anywhere in the loop).
// EPI 0: cc<1536 -> U0 = bf16(v) [u half]; else U1 = bf16(silu(v)) [gate]
// EPI 1: cc<16 -> F0 (Bm); cc<32 -> F1 (Cm); cc<Nstore -> U0 = bf16(softplus)
// EPI 2: U0[pidx(row,cc,48)] = bf16(v * Eb[row,cc])
// EPI 3: F0[row*768+cc] = v + Ef[row*768+cc]
template <int NBX, int EPI>
__global__ __launch_bounds__(256, 3)
void gemm_db(const u16* __restrict__ Ap, const u16* __restrict__ Bp,
             float* __restrict__ F0, float* __restrict__ F1,
             u16* __restrict__ U0, u16* __restrict__ U1,
             const float* __restrict__ Ef, const u16* __restrict__ Eb,
             int K, int Nstore) {
  const int KS = K >> 5;
  __shared__ uint4 lds[2][1024];          // 2 x 16KB: chunks 0-7 = A, 8-15 = B
  const int tid = threadIdx.x;
  const int wave = tid >> 6, lane = tid & 63;
  const int chunk = tid >> 4, part = tid & 15;
  const int u = blockIdx.x;
  const int xcd = u & 7, s = u >> 3;
  const int bmt = xcd * 4 + s / NBX;      // 128-row tile index (M=4096 -> 32)
  const int bnt = s % NBX;

  const long tile = (chunk < 8) ? (long)(bmt * 8 + chunk) : (long)(bnt * 8 + (chunk - 8));
  const uint4* src = (const uint4*)((chunk < 8 ? Ap : Bp) + tile * (long)KS * 512) + part * 4;
  const int ldsoff = chunk * 64 + part * 4;

  uint4 ra[4], rb[4];
  auto loadg = [&](uint4 (&r)[4], int kk) {
    const uint4* p = src + (long)kk * 64;
#pragma unroll
    for (int q = 0; q < 4; ++q) r[q] = p[q];
  };
  auto writes = [&](uint4 (&r)[4], int b) {
#pragma unroll
    for (int q = 0; q < 4; ++q) lds[b][ldsoff + q] = r[q];
  };

  f32x4 acc[4][4] = {};
  const int wm = wave >> 1, wn = wave & 1;

  // prologue: tile0 -> ra -> buf0; tile1 -> rb (in flight)
  loadg(ra, 0);
  loadg(rb, 1);
  writes(ra, 0);                          // auto vmcnt waits ra only
  __builtin_amdgcn_s_waitcnt(0xC07F);     // lgkmcnt(0), vm untouched
  __builtin_amdgcn_s_barrier();

  for (int k = 0; k < KS; ++k) {
    const int cur = k & 1;
    const bool even = (k & 1) == 0;
    if (k + 2 < KS) loadg(even ? ra : rb, k + 2);   // issue early
    bf16x8 af[4], bfv[4];
#pragma unroll
    for (int i = 0; i < 4; ++i)
      af[i] = *(const bf16x8*)&lds[cur][(wm * 4 + i) * 64 + lane];
#pragma unroll
    for (int j = 0; j < 4; ++j)
      bfv[j] = *(const bf16x8*)&lds[cur][(8 + wn * 4 + j) * 64 + lane];
    if (k + 1 < KS) {
      writes(even ? rb : ra, cur ^ 1);    // auto vmcnt(4): waits older 4 only
      __builtin_amdgcn_s_waitcnt(0xC07F); // lgkmcnt(0): my reads+writes landed
      __builtin_amdgcn_s_barrier();
    }
#pragma unroll
    for (int i = 0; i < 4; ++i)
#pragma unroll
      for (int j = 0; j < 4; ++j)
        acc[i][j] = __builtin_amdgcn_mfma_f32_16x16x32_bf16(af[i], bfv[j], acc[i][j], 0, 0, 0);
  }

  const int l16 = lane & 15, l4 = lane >> 4;
#pragma unroll
  for (int i = 0; i < 4; ++i) {
    const long rr = (long)bmt * 128 + (wm * 4 + i) * 16 + l4 * 4;
#pragma unroll
    for (int j = 0; j < 4; ++j) {
      const int cc = bnt * 128 + (wn * 4 + j) * 16 + l16;
#pragma unroll
      for (int r = 0; r < 4; ++r) {
        const long row = rr + r;
        const float v = acc[i][j][r];
        if (EPI == 0) {
          if (cc < 1536) U0[row * 1536 + cc] = f2b(v);
          else {
            float sv = v / (1.f + __expf(-v));
            U1[row * 1536 + (cc - 1536)] = f2b(sv);
          }
        } else if (EPI == 1) {
          if (cc < 16) F0[row * 16 + cc] = v;
          else if (cc < 32) F1[row * 16 + (cc - 16)] = v;
          else if (cc < Nstore) {
            float sp = (v > 20.f) ? v : log1pf(__expf(v));
            U0[row * 1536 + (cc - 32)] = f2b(sp);
          }
        } else if (EPI == 2) {
          float g = b2f(Eb[row * 1536 + cc]);
          U0[pidx(row, cc, 48)] = f2b(v * g);
        } else {
          F0[row * 768 + cc] = v + Ef[row * 768 + cc];
        }
      }
    }
  }
}

// ---------------- depthwise causal conv(K=4) + SiLU -> flat + packed bf16 -------
__global__ __launch_bounds__(256)
void conv_silu(const u16* __restrict__ xpub, const float* __restrict__ cw,
               u16* __restrict__ ub, u16* __restrict__ ubp) {
  const int c = blockIdx.x * 256 + threadIdx.x;
  const long m = blockIdx.y;
  const int t = (int)(m & (SEQ - 1));
  const float w0 = cw[c * 4 + 0], w1 = cw[c * 4 + 1], w2 = cw[c * 4 + 2], w3 = cw[c * 4 + 3];
  float acc = w3 * b2f(xpub[m * 1536 + c]);
  if (t >= 1) acc += w2 * b2f(xpub[(m - 1) * 1536 + c]);
  if (t >= 2) acc += w1 * b2f(xpub[(m - 2) * 1536 + c]);
  if (t >= 3) acc += w0 * b2f(xpub[(m - 3) * 1536 + c]);
  const float s = acc / (1.f + __expf(-acc));
  const u16 sb = f2b(s);
  ub[m * 1536 + c] = sb;
  ubp[pidx(m, c, 48)] = sb;
}

// ---------------- scan phase A: per-chunk (P, Q) from h=0, 4 states/thread ------
__global__ __launch_bounds__(256)
void scan_phaseA(const u16* __restrict__ dlt, const u16* __restrict__ ub,
                 const float* __restrict__ Bm, const float* __restrict__ A_log,
                 float* __restrict__ P, float* __restrict__ Q) {
  const int tid = threadIdx.x;
  const int cl = tid >> 2;
  const int sg = tid & 3;
  const int c = blockIdx.x * 64 + cl;
  const int b = blockIdx.y;
  const int ch = blockIdx.z;
  float a2[4];
#pragma unroll
  for (int j = 0; j < 4; ++j) a2[j] = -__expf(A_log[sg * 4 + j]) * LOG2E;
  float h[4] = {0.f, 0.f, 0.f, 0.f};
  float sumd = 0.f;
  const long base = (long)b * SEQ + (long)ch * CHUNK;
  for (int t = 0; t < CHUNK; ++t) {
    const long m = base + t;
    const float d = b2f(dlt[m * 1536 + c]);
    const float du = d * b2f(ub[m * 1536 + c]);
    sumd += d;
    const f32x4 Bv = *(const f32x4*)&Bm[m * 16 + sg * 4];
#pragma unroll
    for (int j = 0; j < 4; ++j) {
      const float e = exp2f(a2[j] * d);
      h[j] = e * h[j] + du * Bv[j];
    }
  }
  const long sb = (((long)b * NCHUNK + ch) * NST + sg * 4) * 1536 + c;
#pragma unroll
  for (int j = 0; j < 4; ++j) {
    Q[sb + (long)j * 1536] = h[j];
    P[sb + (long)j * 1536] = exp2f(a2[j] * sumd);
  }
}

// ---------------- scan phase B: serial combine over chunks (hs aliases P) -------
__global__ __launch_bounds__(256)
void scan_phaseB(float* __restrict__ P, const float* __restrict__ Q) {
  const long g = (long)blockIdx.x * 256 + threadIdx.x;   // BATCH*NST*INNER
  const int c = (int)(g % 1536);
  const int n = (int)((g / 1536) % NST);
  const int b = (int)(g / (1536 * NST));
  float h = 0.f;
  for (int ch = 0; ch < NCHUNK; ++ch) {
    const long idx = (((long)b * NCHUNK + ch) * NST + n) * 1536 + c;
    const float p = P[idx];
    const float q = Q[idx];
    P[idx] = h;              // hs written in place of P (read-before-write)
    h = p * h + q;
  }
}

// ---------------- scan phase C: replay with true h_start, emit ys packed --------
__global__ __launch_bounds__(256)
void scan_phaseC(const u16* __restrict__ dlt, const u16* __restrict__ ub,
                 const float* __restrict__ Bm, const float* __restrict__ Cm,
                 const float* __restrict__ A_log, const float* __restrict__ Dv,
                 const float* __restrict__ hs, u16* __restrict__ ysp) {
  const int tid = threadIdx.x;
  const int cl = tid >> 2;
  const int sg = tid & 3;
  const int c = blockIdx.x * 64 + cl;
  const int b = blockIdx.y;
  const int ch = blockIdx.z;
  float a2[4];
#pragma unroll
  for (int j = 0; j < 4; ++j) a2[j] = -__expf(A_log[sg * 4 + j]) * LOG2E;
  float h[4];
  const long sb = (((long)b * NCHUNK + ch) * NST + sg * 4) * 1536 + c;
#pragma unroll
  for (int j = 0; j < 4; ++j) h[j] = hs[sb + (long)j * 1536];
  const float Dc = Dv[c];
  const long base = (long)b * SEQ + (long)ch * CHUNK;
  for (int t = 0; t < CHUNK; ++t) {
    const long m = base + t;
    const float d = b2f(dlt[m * 1536 + c]);
    const float uu = b2f(ub[m * 1536 + c]);
    const float du = d * uu;
    const f32x4 Bv = *(const f32x4*)&Bm[m * 16 + sg * 4];
    const f32x4 Cv = *(const f32x4*)&Cm[m * 16 + sg * 4];
    float y = (sg == 0) ? Dc * uu : 0.f;
#pragma unroll
    for (int j = 0; j < 4; ++j) {
      const float e = exp2f(a2[j] * d);
      h[j] = e * h[j] + du * Bv[j];
      y += h[j] * Cv[j];
    }
    y += __shfl_xor(y, 1);
    y += __shfl_xor(y, 2);
    if (sg == 0) ysp[pidx(m, c, 48)] = f2b(y);
  }
}

extern "C" void kernel_launch(void* const* d_in, const int* in_sizes, int n_in,
                              void* d_out, int out_size, void* d_ws, size_t ws_size,
                              hipStream_t stream) {
  const float* x     = (const float*)d_in[0];
  const float* nw    = (const float*)d_in[1];
  const float* nb    = (const float*)d_in[2];
  const float* W_in  = (const float*)d_in[3];
  const float* cw    = (const float*)d_in[4];
  const float* W_xp  = (const float*)d_in[5];
  const float* A_log = (const float*)d_in[6];
  const float* Dv    = (const float*)d_in[7];
  const float* W_so  = (const float*)d_in[8];
  const float* W_out = (const float*)d_in[9];
  float* out = (float*)d_out;

  char* w = (char*)d_ws;
  auto alloc = [&](size_t bytes) {
    char* p = w;
    w += (bytes + 255) & ~(size_t)255;
    return p;
  };
  u16*   xnp   = (u16*)  alloc((size_t)MTOK * HID * 2);    // packed, KS=24
  u16*   WpIn  = (u16*)  alloc((size_t)3072 * 768 * 2);    // packed
  u16*   xpub  = (u16*)  alloc((size_t)MTOK * 1536 * 2);   // u half, bf16 flat
  u16*   sg    = (u16*)  alloc((size_t)MTOK * 1536 * 2);   // silu(gate), bf16 flat
  u16*   ub    = (u16*)  alloc((size_t)MTOK * 1536 * 2);   // silu(conv(u)), flat
  u16*   ubp   = (u16*)  alloc((size_t)MTOK * 1536 * 2);   // same, packed KS=48
  u16*   WpXp  = (u16*)  alloc((size_t)1664 * 1536 * 2);   // packed
  float* Bmv   = (float*)alloc((size_t)MTOK * 16 * 4);
  float* Cmv   = (float*)alloc((size_t)MTOK * 16 * 4);
  u16*   dlt   = (u16*)  alloc((size_t)MTOK * 1536 * 2);   // softplus(delta), flat
  float* P     = (float*)alloc((size_t)BATCH * NCHUNK * NST * 1536 * 4);  // becomes hs
  float* Q     = (float*)alloc((size_t)BATCH * NCHUNK * NST * 1536 * 4);
  u16*   ysp   = (u16*)  alloc((size_t)MTOK * 1536 * 2);   // packed KS=48
  u16*   WpSo  = (u16*)  alloc((size_t)1536 * 1536 * 2);   // packed
  u16*   zbp   = (u16*)  alloc((size_t)MTOK * 1536 * 2);   // packed KS=48
  u16*   WpOut = (u16*)  alloc((size_t)768 * 1536 * 2);    // packed

  ln_kernel<<<MTOK, 256, 0, stream>>>(x, nw, nb, xnp);
  pack_w<<<dim3(48, 24), 256, 0, stream>>>(W_in,  WpIn,  768,  3072);
  pack_w<<<dim3(26, 48), 256, 0, stream>>>(W_xp,  WpXp,  1536, 1568);
  pack_w<<<dim3(24, 48), 256, 0, stream>>>(W_so,  WpSo,  1536, 1536);
  pack_w<<<dim3(12, 48), 256, 0, stream>>>(W_out, WpOut, 1536, 768);

  // gemm0: 4096x3072, K=768  -> 24*32 = 768 blocks
  gemm_db<24, 0><<<768, 256, 0, stream>>>(xnp, WpIn, nullptr, nullptr, xpub, sg, nullptr, nullptr, 768, 3072);
  conv_silu<<<dim3(6, MTOK), 256, 0, stream>>>(xpub, cw, ub, ubp);
  // gemm1: 4096x1664, K=1536 -> 13*32 = 416 blocks
  gemm_db<13, 1><<<416, 256, 0, stream>>>(ubp, WpXp, Bmv, Cmv, dlt, nullptr, nullptr, nullptr, 1536, 1568);
  scan_phaseA<<<dim3(24, 2, NCHUNK), 256, 0, stream>>>(dlt, ub, Bmv, A_log, P, Q);
  scan_phaseB<<<192, 256, 0, stream>>>(P, Q);
  scan_phaseC<<<dim3(24, 2, NCHUNK), 256, 0, stream>>>(dlt, ub, Bmv, Cmv, A_log, Dv, P, ysp);
  // gemm2: 4096x1536, K=1536 -> 12*32 = 384 blocks
  gemm_db<12, 2><<<384, 256, 0, stream>>>(ysp, WpSo, nullptr, nullptr, zbp, nullptr, nullptr, sg, 1536, 1536);
  // gemm3: 4096x768,  K=1536 -> 6*32 = 192 blocks
  gemm_db<6, 3><<<192, 256, 0, stream>>>(zbp, WpOut, out, nullptr, nullptr, nullptr, x, nullptr, 1536, 768);
}

// Round 8
// 657.183 us; speedup vs baseline: 1.0070x; 1.0070x over previous
//
#include <hip/hip_runtime.h>
#include <cstdint>
#include <cmath>

#define HID 768
#define INNER 1536
#define NST 16
#define SEQ 2048
#define BATCH 2
#define MTOK 4096      // BATCH*SEQ
#define CHUNK 32
#define NCHUNK 64      // SEQ/CHUNK
#define LOG2E 1.44269504088896f

typedef unsigned short u16;
typedef __bf16 bf16x8 __attribute__((ext_vector_type(8)));
typedef float f32x4 __attribute__((ext_vector_type(4)));
typedef u16 u16x8 __attribute__((ext_vector_type(8)));

__device__ __forceinline__ u16 f2b(float f) {
  union { float f; unsigned u; } a; a.f = f;
  unsigned r = a.u + 0x7FFFu + ((a.u >> 16) & 1u);
  return (u16)(r >> 16);
}
__device__ __forceinline__ float b2f(u16 h) {
  union { unsigned u; float f; } a; a.u = ((unsigned)h) << 16; return a.f;
}

// packed fragment layout: element (m,k) of an [M][K] bf16 matrix lives at
//   chunk = ((m>>4)*KS + (k>>5))*64 + ((k>>3)&3)*16 + (m&15),  elem = chunk*8 + (k&7)
// where KS = K/32. Tile t, kstep ks = contiguous 1KB block.
__device__ __forceinline__ long pidx(long m, int k, int KS) {
  return (((m >> 4) * (long)KS + (k >> 5)) * 64 + ((k >> 3) & 3) * 16 + (m & 15)) * 8 + (k & 7);
}

// ---------------- LayerNorm + cast to bf16 (packed, KS=24) ----------------
__global__ __launch_bounds__(256)
void ln_kernel(const float* __restrict__ x, const float* __restrict__ w,
               const float* __restrict__ b, u16* __restrict__ xnp) {
  const long row = blockIdx.x;
  const float* xr = x + row * HID;
  const int t = threadIdx.x;
  float v0 = xr[t], v1 = xr[t + 256], v2 = xr[t + 512];
  float s1 = v0 + v1 + v2;
  float s2 = v0 * v0 + v1 * v1 + v2 * v2;
#pragma unroll
  for (int o = 32; o > 0; o >>= 1) { s1 += __shfl_down(s1, o); s2 += __shfl_down(s2, o); }
  __shared__ float r1[4], r2[4];
  if ((t & 63) == 0) { r1[t >> 6] = s1; r2[t >> 6] = s2; }
  __syncthreads();
  s1 = r1[0] + r1[1] + r1[2] + r1[3];
  s2 = r2[0] + r2[1] + r2[2] + r2[3];
  const float mu = s1 * (1.f / HID);
  float var = s2 * (1.f / HID) - mu * mu;
  const float rs = rsqrtf(var + 1e-5f);
  xnp[pidx(row, t,       24)] = f2b((v0 - mu) * rs * w[t]       + b[t]);
  xnp[pidx(row, t + 256, 24)] = f2b((v1 - mu) * rs * w[t + 256] + b[t + 256]);
  xnp[pidx(row, t + 512, 24)] = f2b((v2 - mu) * rs * w[t + 512] + b[t + 512]);
}

// ---------------- fp32 W[K][N] -> packed bf16 fragments (B-operand) ----------------
__global__ __launch_bounds__(256)
void pack_w(const float* __restrict__ W, u16* __restrict__ Bp, int K, int N) {
  __shared__ float tb[32][65];
  const int t = threadIdx.x;
  const int n0 = blockIdx.x * 64;
  const int ks = blockIdx.y;
  const int k0 = ks * 32;
  const int KS = K >> 5;
  {
    const int col = t & 63, row0 = t >> 6;
    const int nn = n0 + col;
#pragma unroll
    for (int rr = 0; rr < 8; ++rr) {
      const int kk = k0 + row0 + rr * 4;
      tb[row0 + rr * 4][col] = (nn < N) ? W[(long)kk * N + nn] : 0.f;
    }
  }
  __syncthreads();
  const int ntl = t >> 6, l4 = (t >> 4) & 3, l16 = t & 15;
  const int nl = ntl * 16 + l16;
  u16x8 outv;
#pragma unroll
  for (int wdx = 0; wdx < 8; ++wdx) outv[wdx] = f2b(tb[l4 * 8 + wdx][nl]);
  const long tile = (n0 >> 4) + ntl;
  *(u16x8*)&Bp[(tile * KS + ks) * 512 + (l4 * 16 + l16) * 8] = outv;
}

// ---------------- AITER-style pipelined GEMM: 128x128 tile, LDS dbuf ------------
// 3-stage pipeline, K-loop unrolled x2 so prefetch regs ra/rb are referenced
// statically (NO runtime array selection -> no scratch demotion).
// Staging swizzle: thread (chunk,part) covers uint4 indices part+q*16 -> each
// ds_write_b128 has 16 lanes x 16B contiguous (conflict-free); global loads
// 256B-contiguous per 16-lane group. One raw s_barrier per k-step, only
// lgkmcnt(0) drained; compiler emits vmcnt(4) at writes -> newer 4 global
// loads stay in flight across the barrier.
template <int NBX, int EPI>
__global__ __launch_bounds__(256)
void gemm_db(const u16* __restrict__ Ap, const u16* __restrict__ Bp,
             float* __restrict__ F0, float* __restrict__ F1,
             u16* __restrict__ U0, u16* __restrict__ U1,
             const float* __restrict__ Ef, const u16* __restrict__ Eb,
             int K, int Nstore) {
  const int KS = K >> 5;                  // even (24 or 48)
  __shared__ uint4 lds[2][1024];          // 2 x 16KB: chunks 0-7 = A, 8-15 = B
  const int tid = threadIdx.x;
  const int wave = tid >> 6, lane = tid & 63;
  const int chunk = tid >> 4, part = tid & 15;
  const int u = blockIdx.x;
  const int xcd = u & 7, s = u >> 3;
  const int bmt = xcd * 4 + s / NBX;      // 128-row tile index (M=4096 -> 32)
  const int bnt = s % NBX;

  const long tile = (chunk < 8) ? (long)(bmt * 8 + chunk) : (long)(bnt * 8 + (chunk - 8));
  const uint4* srcb = (const uint4*)((chunk < 8 ? Ap : Bp) + tile * (long)KS * 512) + part;
  uint4* wd0 = &lds[0][chunk * 64 + part];
  uint4* wd1 = &lds[1][chunk * 64 + part];

  uint4 ra[4], rb[4];
  auto loadgA = [&](int kk) {
    const uint4* p = srcb + (long)kk * 64;
#pragma unroll
    for (int q = 0; q < 4; ++q) ra[q] = p[q * 16];
  };
  auto loadgB = [&](int kk) {
    const uint4* p = srcb + (long)kk * 64;
#pragma unroll
    for (int q = 0; q < 4; ++q) rb[q] = p[q * 16];
  };
  auto writesA = [&](uint4* d) {
#pragma unroll
    for (int q = 0; q < 4; ++q) d[q * 16] = ra[q];
  };
  auto writesB = [&](uint4* d) {
#pragma unroll
    for (int q = 0; q < 4; ++q) d[q * 16] = rb[q];
  };

  f32x4 acc[4][4] = {};
  const int wm = wave >> 1, wn = wave & 1;

  bf16x8 af[4], bfv[4];
  auto readfrags = [&](int b) {
#pragma unroll
    for (int i = 0; i < 4; ++i)
      af[i] = *(const bf16x8*)&lds[b][(wm * 4 + i) * 64 + lane];
#pragma unroll
    for (int j = 0; j < 4; ++j)
      bfv[j] = *(const bf16x8*)&lds[b][(8 + wn * 4 + j) * 64 + lane];
  };
  auto mfmall = [&]() {
#pragma unroll
    for (int i = 0; i < 4; ++i)
#pragma unroll
      for (int j = 0; j < 4; ++j)
        acc[i][j] = __builtin_amdgcn_mfma_f32_16x16x32_bf16(af[i], bfv[j], acc[i][j], 0, 0, 0);
  };

  // prologue: tile0 -> ra -> buf0; tile1 -> rb (left in flight)
  loadgA(0);
  loadgB(1);
  writesA(wd0);                           // vmcnt waits ra only (rb newer, in flight)
  __builtin_amdgcn_s_waitcnt(0xC07F);     // lgkmcnt(0); vmcnt untouched
  __builtin_amdgcn_s_barrier();

  for (int k = 0; k < KS; k += 2) {
    // even phase: compute tile k from buf0; stage rb(tile k+1)->buf1; ra <- tile k+2
    if (k + 2 < KS) loadgA(k + 2);
    readfrags(0);
    writesB(wd1);                         // vmcnt(4): waits rb, ra stays in flight
    __builtin_amdgcn_s_waitcnt(0xC07F);
    __builtin_amdgcn_s_barrier();
    mfmall();
    // odd phase: compute tile k+1 from buf1; stage ra(tile k+2)->buf0; rb <- tile k+3
    if (k + 3 < KS) loadgB(k + 3);
    readfrags(1);
    if (k + 2 < KS) {
      writesA(wd0);
      __builtin_amdgcn_s_waitcnt(0xC07F);
      __builtin_amdgcn_s_barrier();
    }
    mfmall();
  }

  const int l16 = lane & 15, l4 = lane >> 4;
#pragma unroll
  for (int i = 0; i < 4; ++i) {
    const long rr = (long)bmt * 128 + (wm * 4 + i) * 16 + l4 * 4;
#pragma unroll
    for (int j = 0; j < 4; ++j) {
      const int cc = bnt * 128 + (wn * 4 + j) * 16 + l16;
#pragma unroll
      for (int r = 0; r < 4; ++r) {
        const long row = rr + r;
        const float v = acc[i][j][r];
        if (EPI == 0) {
          if (cc < 1536) U0[row * 1536 + cc] = f2b(v);
          else {
            float sv = v / (1.f + __expf(-v));
            U1[row * 1536 + (cc - 1536)] = f2b(sv);
          }
        } else if (EPI == 1) {
          if (cc < 16) F0[row * 16 + cc] = v;
          else if (cc < 32) F1[row * 16 + (cc - 16)] = v;
          else if (cc < Nstore) {
            float sp = (v > 20.f) ? v : log1pf(__expf(v));
            U0[row * 1536 + (cc - 32)] = f2b(sp);
          }
        } else if (EPI == 2) {
          float g = b2f(Eb[row * 1536 + cc]);
          U0[pidx(row, cc, 48)] = f2b(v * g);
        } else {
          F0[row * 768 + cc] = v + Ef[row * 768 + cc];
        }
      }
    }
  }
}

// ---------------- depthwise causal conv(K=4) + SiLU -> flat + packed bf16 -------
__global__ __launch_bounds__(256)
void conv_silu(const u16* __restrict__ xpub, const float* __restrict__ cw,
               u16* __restrict__ ub, u16* __restrict__ ubp) {
  const int c = blockIdx.x * 256 + threadIdx.x;
  const long m = blockIdx.y;
  const int t = (int)(m & (SEQ - 1));
  const float w0 = cw[c * 4 + 0], w1 = cw[c * 4 + 1], w2 = cw[c * 4 + 2], w3 = cw[c * 4 + 3];
  float acc = w3 * b2f(xpub[m * 1536 + c]);
  if (t >= 1) acc += w2 * b2f(xpub[(m - 1) * 1536 + c]);
  if (t >= 2) acc += w1 * b2f(xpub[(m - 2) * 1536 + c]);
  if (t >= 3) acc += w0 * b2f(xpub[(m - 3) * 1536 + c]);
  const float s = acc / (1.f + __expf(-acc));
  const u16 sb = f2b(s);
  ub[m * 1536 + c] = sb;
  ubp[pidx(m, c, 48)] = sb;
}

// ---------------- scan phase A: per-chunk (P, Q) from h=0, 4 states/thread ------
__global__ __launch_bounds__(256)
void scan_phaseA(const u16* __restrict__ dlt, const u16* __restrict__ ub,
                 const float* __restrict__ Bm, const float* __restrict__ A_log,
                 float* __restrict__ P, float* __restrict__ Q) {
  const int tid = threadIdx.x;
  const int cl = tid >> 2;
  const int sg = tid & 3;
  const int c = blockIdx.x * 64 + cl;
  const int b = blockIdx.y;
  const int ch = blockIdx.z;
  float a2[4];
#pragma unroll
  for (int j = 0; j < 4; ++j) a2[j] = -__expf(A_log[sg * 4 + j]) * LOG2E;
  float h[4] = {0.f, 0.f, 0.f, 0.f};
  float sumd = 0.f;
  const long base = (long)b * SEQ + (long)ch * CHUNK;
  for (int t = 0; t < CHUNK; ++t) {
    const long m = base + t;
    const float d = b2f(dlt[m * 1536 + c]);
    const float du = d * b2f(ub[m * 1536 + c]);
    sumd += d;
    const f32x4 Bv = *(const f32x4*)&Bm[m * 16 + sg * 4];
#pragma unroll
    for (int j = 0; j < 4; ++j) {
      const float e = exp2f(a2[j] * d);
      h[j] = e * h[j] + du * Bv[j];
    }
  }
  const long sb = (((long)b * NCHUNK + ch) * NST + sg * 4) * 1536 + c;
#pragma unroll
  for (int j = 0; j < 4; ++j) {
    Q[sb + (long)j * 1536] = h[j];
    P[sb + (long)j * 1536] = exp2f(a2[j] * sumd);
  }
}

// ---------------- scan phase B: serial combine over chunks (hs aliases P) -------
__global__ __launch_bounds__(256)
void scan_phaseB(float* __restrict__ P, const float* __restrict__ Q) {
  const long g = (long)blockIdx.x * 256 + threadIdx.x;   // BATCH*NST*INNER
  const int c = (int)(g % 1536);
  const int n = (int)((g / 1536) % NST);
  const int b = (int)(g / (1536 * NST));
  float h = 0.f;
  for (int ch = 0; ch < NCHUNK; ++ch) {
    const long idx = (((long)b * NCHUNK + ch) * NST + n) * 1536 + c;
    const float p = P[idx];
    const float q = Q[idx];
    P[idx] = h;              // hs written in place of P (read-before-write)
    h = p * h + q;
  }
}

// ---------------- scan phase C: replay with true h_start, emit ys packed --------
__global__ __launch_bounds__(256)
void scan_phaseC(const u16* __restrict__ dlt, const u16* __restrict__ ub,
                 const float* __restrict__ Bm, const float* __restrict__ Cm,
                 const float* __restrict__ A_log, const float* __restrict__ Dv,
                 const float* __restrict__ hs, u16* __restrict__ ysp) {
  const int tid = threadIdx.x;
  const int cl = tid >> 2;
  const int sg = tid & 3;
  const int c = blockIdx.x * 64 + cl;
  const int b = blockIdx.y;
  const int ch = blockIdx.z;
  float a2[4];
#pragma unroll
  for (int j = 0; j < 4; ++j) a2[j] = -__expf(A_log[sg * 4 + j]) * LOG2E;
  float h[4];
  const long sb = (((long)b * NCHUNK + ch) * NST + sg * 4) * 1536 + c;
#pragma unroll
  for (int j = 0; j < 4; ++j) h[j] = hs[sb + (long)j * 1536];
  const float Dc = Dv[c];
  const long base = (long)b * SEQ + (long)ch * CHUNK;
  for (int t = 0; t < CHUNK; ++t) {
    const long m = base + t;
    const float d = b2f(dlt[m * 1536 + c]);
    const float uu = b2f(ub[m * 1536 + c]);
    const float du = d * uu;
    const f32x4 Bv = *(const f32x4*)&Bm[m * 16 + sg * 4];
    const f32x4 Cv = *(const f32x4*)&Cm[m * 16 + sg * 4];
    float y = (sg == 0) ? Dc * uu : 0.f;
#pragma unroll
    for (int j = 0; j < 4; ++j) {
      const float e = exp2f(a2[j] * d);
      h[j] = e * h[j] + du * Bv[j];
      y += h[j] * Cv[j];
    }
    y += __shfl_xor(y, 1);
    y += __shfl_xor(y, 2);
    if (sg == 0) ysp[pidx(m, c, 48)] = f2b(y);
  }
}

extern "C" void kernel_launch(void* const* d_in, const int* in_sizes, int n_in,
                              void* d_out, int out_size, void* d_ws, size_t ws_size,
                              hipStream_t stream) {
  const float* x     = (const float*)d_in[0];
  const float* nw    = (const float*)d_in[1];
  const float* nb    = (const float*)d_in[2];
  const float* W_in  = (const float*)d_in[3];
  const float* cw    = (const float*)d_in[4];
  const float* W_xp  = (const float*)d_in[5];
  const float* A_log = (const float*)d_in[6];
  const float* Dv    = (const float*)d_in[7];
  const float* W_so  = (const float*)d_in[8];
  const float* W_out = (const float*)d_in[9];
  float* out = (float*)d_out;

  char* w = (char*)d_ws;
  auto alloc = [&](size_t bytes) {
    char* p = w;
    w += (bytes + 255) & ~(size_t)255;
    return p;
  };
  u16*   xnp   = (u16*)  alloc((size_t)MTOK * HID * 2);    // packed, KS=24
  u16*   WpIn  = (u16*)  alloc((size_t)3072 * 768 * 2);    // packed
  u16*   xpub  = (u16*)  alloc((size_t)MTOK * 1536 * 2);   // u half, bf16 flat
  u16*   sg    = (u16*)  alloc((size_t)MTOK * 1536 * 2);   // silu(gate), bf16 flat
  u16*   ub    = (u16*)  alloc((size_t)MTOK * 1536 * 2);   // silu(conv(u)), flat
  u16*   ubp   = (u16*)  alloc((size_t)MTOK * 1536 * 2);   // same, packed KS=48
  u16*   WpXp  = (u16*)  alloc((size_t)1664 * 1536 * 2);   // packed
  float* Bmv   = (float*)alloc((size_t)MTOK * 16 * 4);
  float* Cmv   = (float*)alloc((size_t)MTOK * 16 * 4);
  u16*   dlt   = (u16*)  alloc((size_t)MTOK * 1536 * 2);   // softplus(delta), flat
  float* P     = (float*)alloc((size_t)BATCH * NCHUNK * NST * 1536 * 4);  // becomes hs
  float* Q     = (float*)alloc((size_t)BATCH * NCHUNK * NST * 1536 * 4);
  u16*   ysp   = (u16*)  alloc((size_t)MTOK * 1536 * 2);   // packed KS=48
  u16*   WpSo  = (u16*)  alloc((size_t)1536 * 1536 * 2);   // packed
  u16*   zbp   = (u16*)  alloc((size_t)MTOK * 1536 * 2);   // packed KS=48
  u16*   WpOut = (u16*)  alloc((size_t)768 * 1536 * 2);    // packed

  ln_kernel<<<MTOK, 256, 0, stream>>>(x, nw, nb, xnp);
  pack_w<<<dim3(48, 24), 256, 0, stream>>>(W_in,  WpIn,  768,  3072);
  pack_w<<<dim3(26, 48), 256, 0, stream>>>(W_xp,  WpXp,  1536, 1568);
  pack_w<<<dim3(24, 48), 256, 0, stream>>>(W_so,  WpSo,  1536, 1536);
  pack_w<<<dim3(12, 48), 256, 0, stream>>>(W_out, WpOut, 1536, 768);

  // gemm0: 4096x3072, K=768  -> 24*32 = 768 blocks
  gemm_db<24, 0><<<768, 256, 0, stream>>>(xnp, WpIn, nullptr, nullptr, xpub, sg, nullptr, nullptr, 768, 3072);
  conv_silu<<<dim3(6, MTOK), 256, 0, stream>>>(xpub, cw, ub, ubp);
  // gemm1: 4096x1664, K=1536 -> 13*32 = 416 blocks
  gemm_db<13, 1><<<416, 256, 0, stream>>>(ubp, WpXp, Bmv, Cmv, dlt, nullptr, nullptr, nullptr, 1536, 1568);
  scan_phaseA<<<dim3(24, 2, NCHUNK), 256, 0, stream>>>(dlt, ub, Bmv, A_log, P, Q);
  scan_phaseB<<<192, 256, 0, stream>>>(P, Q);
  scan_phaseC<<<dim3(24, 2, NCHUNK), 256, 0, stream>>>(dlt, ub, Bmv, Cmv, A_log, Dv, P, ysp);
  // gemm2: 4096x1536, K=1536 -> 12*32 = 384 blocks
  gemm_db<12, 2><<<384, 256, 0, stream>>>(ysp, WpSo, nullptr, nullptr, zbp, nullptr, nullptr, sg, 1536, 1536);
  // gemm3: 4096x768,  K=1536 -> 6*32 = 192 blocks
  gemm_db<6, 3><<<192, 256, 0, stream>>>(zbp, WpOut, out, nullptr, nullptr, nullptr, x, nullptr, 1536, 768);
}